// Round 6
// baseline (450.148 us; speedup 1.0000x reference)
//
#include <hip/hip_runtime.h>
#include <hip/hip_bf16.h>

// Attention_50946902065218: Bahdanau-style attention
// B=256, L=196, E=2048, D=1024, A=512
// Pipeline:
//  k_wepack: We fp32 -> bf16, packed [kb][n][kg^swz(n)][e] (swizzle BAKED IN so
//            the linear global_load_lds copy lands bank-conflict-free)
//  k_bias2 : bias2[b][a] = be[a] + bd[a] + dec[b]@Wd[:,a]
//  k_gemm_score (v6): m97-geometry 128x128 tile, 4 waves (2x2), BK=32,
//     counted-vmcnt 2-phase dbuf, XCD-chunked swizzle (A-tile L2 reuse
//     across the 4 N-blocks), partial wf-dot scores -> scoresP[4][M]
//  k_softmax: sum 4 partials + mask + softmax over L -> alpha
//  k_awe (v3): 1 block per batch, contiguous 1.6MB stream, unroll-4

#define B_ 256
#define L_ 196
#define E_ 2048
#define D_ 1024
#define A_ 512
#define M_TOT (B_ * L_)   // 50176 = 392 * 128

typedef __attribute__((ext_vector_type(8))) short bf16x8;
typedef __attribute__((ext_vector_type(4))) float f32x4;

static __device__ __forceinline__ unsigned short f2bf(float f) {
    union { float f; unsigned u; } u{f};
    unsigned r = u.u + 0x7fffu + ((u.u >> 16) & 1u);   // RNE
    return (unsigned short)(r >> 16);
}

static __device__ __forceinline__ unsigned int pk2(float x, float y) {
    __hip_bfloat162 h = __float22bfloat162_rn(float2{x, y});   // v_cvt_pk_bf16_f32
    return *reinterpret_cast<unsigned int*>(&h);
}

static __device__ __forceinline__ void gload_lds16(const void* g, void* l) {
    __builtin_amdgcn_global_load_lds(
        (const __attribute__((address_space(1))) unsigned int*)g,
        (__attribute__((address_space(3))) unsigned int*)l, 16, 0, 0);
}

// ---------------- kernel 0a: pack We (E x A fp32) -> WeP bf16 -----------------
// Element (k, n): kb=k>>5, kg=(k>>3)&3, e=k&7.
// Stored at kb*16384 + n*32 + (kg ^ ((n>>1)&3))*8 + e   (swizzled 16B slots)
__global__ __launch_bounds__(256) void k_wepack(const float* __restrict__ We,
                                                unsigned short* __restrict__ WeP) {
    int i = blockIdx.x * 256 + threadIdx.x;       // source index over 2048*512
    int k = i >> 9, n = i & 511;
    int kb = k >> 5, kg = (k >> 3) & 3, e = k & 7;
    int kgE = kg ^ ((n >> 1) & 3);
    WeP[(kb << 14) + (n << 5) + (kgE << 3) + e] = f2bf(We[i]);
}

// ---------------- kernel 0b: bias2 = be + bd + dec @ Wd ----------------------
__global__ __launch_bounds__(256) void k_bias2(const float* __restrict__ dec,
                                               const float* __restrict__ Wd,
                                               const float* __restrict__ be,
                                               const float* __restrict__ bd,
                                               float* __restrict__ bias2) {
    int b = blockIdx.x, t = threadIdx.x;
    __shared__ float ds[D_];
    for (int i = t; i < D_; i += 256) ds[i] = dec[b * D_ + i];
    __syncthreads();
    for (int a0 = 0; a0 < A_; a0 += 256) {
        int a = a0 + t;
        float acc = 0.f;
        #pragma unroll 8
        for (int d = 0; d < D_; d++) acc += ds[d] * Wd[d * A_ + a];
        bias2[b * A_ + a] = acc + be[a] + bd[a];
    }
}

// ---------------- kernel 1: fused GEMM + tanh + wf-dot -----------------------
// 1568 blocks (392 mt x 4 nt, XCD-chunked), 256 threads, 4 waves 2x2.
// Wave tile 64x64, acc[4][4]. BK=32, 64 K-steps, counted-vmcnt dbuf pipeline.
__global__ __launch_bounds__(256, 3) void k_gemm_score(
        const float* __restrict__ enc,
        const unsigned short* __restrict__ WeP,
        const float* __restrict__ bias2,
        const float* __restrict__ wf,
        float* __restrict__ scoresP) {
    __shared__ __align__(16) unsigned short aL[2][128 * 32];  // 8 KB each
    __shared__ __align__(16) unsigned short bL[2][128 * 32];  // 8 KB each
    __shared__ float score_lds[4][64];

    const int tid = threadIdx.x;
    // XCD-chunked bijective swizzle: 1568 = 8 * 196; all 4 nt of an mt-group
    // land on the same XCD back-to-back -> A-tile L2 reuse.
    const int raw = blockIdx.x;
    const int wg = (raw & 7) * 196 + (raw >> 3);
    const int mt = wg >> 2, nt = wg & 3;
    const int m0 = mt * 128;

    const int lane = tid & 63;
    const int wid = tid >> 6;
    const int wm = wid >> 1, wn = wid & 1;
    const int kg = lane >> 4, lr = lane & 15;

    // A staging: thread -> row ar (2 thr/row), 16 fp32 at k-half kh
    const int ar = tid >> 1, kh = tid & 1;
    const float* aSrc = enc + (size_t)(m0 + ar) * E_ + kh * 16;
    const int sw = (ar >> 1) & 3;
    const int aOff0 = ar * 32 + (((kh * 2 + 0) ^ sw) << 3);
    const int aOff1 = ar * 32 + (((kh * 2 + 1) ^ sw) << 3);

    // B staging: 2 x gload_lds16 per thread, linear 8KB stripe (pre-swizzled)
    const unsigned short* bSrcLane =
        WeP + nt * 4096 + (size_t)(wid * 1024 + lane * 8);

    auto stageB = [&](int kb, int buf) {
        const unsigned short* s = bSrcLane + ((size_t)kb << 14);
        #pragma unroll
        for (int c = 0; c < 2; c++)
            gload_lds16(s + c * 512, &bL[buf][(wid * 2 + c) * 512]);
    };
    auto loadA = [&](float4 (&v)[4], int t) {
        const float* p = aSrc + t * 32;
        v[0] = *reinterpret_cast<const float4*>(p);
        v[1] = *reinterpret_cast<const float4*>(p + 4);
        v[2] = *reinterpret_cast<const float4*>(p + 8);
        v[3] = *reinterpret_cast<const float4*>(p + 12);
    };
    auto writeA = [&](const float4 (&v)[4], int buf) {
        uint4 lo, hi;
        lo.x = pk2(v[0].x, v[0].y); lo.y = pk2(v[0].z, v[0].w);
        lo.z = pk2(v[1].x, v[1].y); lo.w = pk2(v[1].z, v[1].w);
        hi.x = pk2(v[2].x, v[2].y); hi.y = pk2(v[2].z, v[2].w);
        hi.z = pk2(v[3].x, v[3].y); hi.w = pk2(v[3].z, v[3].w);
        *reinterpret_cast<uint4*>(&aL[buf][aOff0]) = lo;
        *reinterpret_cast<uint4*>(&aL[buf][aOff1]) = hi;
    };

    f32x4 acc[4][4];
    #pragma unroll
    for (int i = 0; i < 4; i++)
        #pragma unroll
        for (int j = 0; j < 4; j++) acc[i][j] = (f32x4){0.f, 0.f, 0.f, 0.f};

    auto computeTile = [&](int buf) {
        bf16x8 bfr[4];
        #pragma unroll
        for (int j = 0; j < 4; j++) {
            int n = wn * 64 + j * 16 + lr;
            bfr[j] = *reinterpret_cast<const bf16x8*>(
                &bL[buf][n * 32 + ((kg ^ ((n >> 1) & 3)) << 3)]);
        }
        #pragma unroll
        for (int i = 0; i < 4; i++) {
            int row = wm * 64 + i * 16 + lr;
            bf16x8 af = *reinterpret_cast<const bf16x8*>(
                &aL[buf][row * 32 + ((kg ^ ((row >> 1) & 3)) << 3)]);
            #pragma unroll
            for (int j = 0; j < 4; j++)
                acc[i][j] = __builtin_amdgcn_mfma_f32_16x16x32_bf16(
                    af, bfr[j], acc[i][j], 0, 0, 0);
        }
    };

    // --- prologue: stage B(0); load A(0),A(1),A(2); write A(0) ---
    stageB(0, 0);
    __builtin_amdgcn_sched_barrier(0);     // stageB vmem first
    float4 av0[4], avH1[4], avH2[4];
    loadA(av0, 0);
    loadA(avH1, 1);
    loadA(avH2, 2);
    writeA(av0, 0);                        // compiler waits av0 (+stageB older)
    asm volatile("s_waitcnt vmcnt(8) lgkmcnt(0)" ::: "memory");
    __builtin_amdgcn_s_barrier();
    __builtin_amdgcn_sched_barrier(0);

    int buf = 0;
    for (int t = 0; t < 63; t++) {
        stageB(t + 1, buf ^ 1);            // 2 vmem (oldest this iter)
        __builtin_amdgcn_sched_barrier(0);
        int tn = (t + 3 > 63) ? 63 : t + 3;
        float4 avN[4];
        loadA(avN, tn);                    // 4 vmem (newest this iter)
        __builtin_amdgcn_sched_barrier(0);
        computeTile(buf);
        writeA(avH1, buf ^ 1);             // value drained 2 barriers ago
        // drain stageB(t+1) + A(t+2); leave A(t+3) x4 in flight
        asm volatile("s_waitcnt vmcnt(4) lgkmcnt(0)" ::: "memory");
        __builtin_amdgcn_s_barrier();
        __builtin_amdgcn_sched_barrier(0);
        #pragma unroll
        for (int q = 0; q < 4; q++) { avH1[q] = avH2[q]; avH2[q] = avN[q]; }
        buf ^= 1;
    }
    computeTile(buf);

    // --- epilogue: tanh + wf dot over this block's 128 cols -> partials ---
    #pragma unroll
    for (int i = 0; i < 4; i++) {
        #pragma unroll
        for (int r = 0; r < 4; r++) {
            int Rw = i * 16 + kg * 4 + r;    // row within wave tile
            int gm = m0 + wm * 64 + Rw;
            int bg = gm / L_;
            float sum = 0.f;
            #pragma unroll
            for (int j = 0; j < 4; j++) {
                int C = nt * 128 + wn * 64 + j * 16 + lr;
                float x = acc[i][j][r] + bias2[bg * A_ + C];
                // fast tanh: 1 - 2/(e^{2x}+1)
                float ex = __expf(2.f * x);
                sum += wf[C] * (1.f - 2.f * __builtin_amdgcn_rcpf(ex + 1.f));
            }
            #pragma unroll
            for (int mk = 1; mk < 16; mk <<= 1) sum += __shfl_xor(sum, mk);
            if (lr == 0) score_lds[wid][Rw] = sum;
        }
    }
    __syncthreads();
    if (tid < 128) {
        int wmp = tid >> 6;
        float s = score_lds[wmp * 2][tid & 63] + score_lds[wmp * 2 + 1][tid & 63];
        scoresP[nt * M_TOT + m0 + tid] = s;
    }
}

// ---------------- kernel 2: sum partials + mask + softmax --------------------
__global__ __launch_bounds__(256) void k_softmax(const float* __restrict__ scoresP,
                                                 const int* __restrict__ mask,
                                                 const float* __restrict__ bfp,
                                                 float* __restrict__ alpha) {
    int b = blockIdx.x, t = threadIdx.x;
    float bfv = bfp[0];
    float v = -INFINITY;
    if (t < L_) {
        int idx = b * L_ + t;
        float sc = scoresP[idx] + scoresP[M_TOT + idx] +
                   scoresP[2 * M_TOT + idx] + scoresP[3 * M_TOT + idx];
        v = (mask[idx] == 0) ? -1e9f : (sc + bfv);
    }
    __shared__ float redm[4], reds[4];
    float m = v;
    #pragma unroll
    for (int s = 1; s < 64; s <<= 1) m = fmaxf(m, __shfl_xor(m, s));
    int w = t >> 6;
    if ((t & 63) == 0) redm[w] = m;
    __syncthreads();
    m = fmaxf(fmaxf(redm[0], redm[1]), fmaxf(redm[2], redm[3]));
    float e = (t < L_) ? expf(v - m) : 0.f;
    float s = e;
    #pragma unroll
    for (int k = 1; k < 64; k <<= 1) s += __shfl_xor(s, k);
    if ((t & 63) == 0) reds[w] = s;
    __syncthreads();
    s = reds[0] + reds[1] + reds[2] + reds[3];
    if (t < L_) alpha[b * L_ + t] = e / s;
}

// ---------------- kernel 3: awe = sum_l alpha * enc --------------------------
// 256 blocks (one per batch), 512 threads cover all E=2048 (float4 each).
// enc[b] is streamed as one contiguous 1.6MB sequential read. Unroll-4.
__global__ __launch_bounds__(512) void k_awe(const float* __restrict__ enc,
                                             const float* __restrict__ alpha,
                                             float* __restrict__ awe) {
    int b = blockIdx.x, t = threadIdx.x;
    __shared__ float al[L_];
    if (t < L_) al[t] = alpha[b * L_ + t];
    __syncthreads();
    const float* base = enc + (size_t)b * L_ * E_ + t * 4;
    float4 a0 = {0.f, 0.f, 0.f, 0.f}, a1 = a0, a2 = a0, a3 = a0;
    for (int l = 0; l < L_; l += 4) {       // 196 = 4*49, exact
        float4 v0 = *reinterpret_cast<const float4*>(base + (size_t)l * E_);
        float4 v1 = *reinterpret_cast<const float4*>(base + (size_t)(l + 1) * E_);
        float4 v2 = *reinterpret_cast<const float4*>(base + (size_t)(l + 2) * E_);
        float4 v3 = *reinterpret_cast<const float4*>(base + (size_t)(l + 3) * E_);
        float c0 = al[l], c1 = al[l + 1], c2 = al[l + 2], c3 = al[l + 3];
        a0.x += c0 * v0.x; a0.y += c0 * v0.y; a0.z += c0 * v0.z; a0.w += c0 * v0.w;
        a1.x += c1 * v1.x; a1.y += c1 * v1.y; a1.z += c1 * v1.z; a1.w += c1 * v1.w;
        a2.x += c2 * v2.x; a2.y += c2 * v2.y; a2.z += c2 * v2.z; a2.w += c2 * v2.w;
        a3.x += c3 * v3.x; a3.y += c3 * v3.y; a3.z += c3 * v3.z; a3.w += c3 * v3.w;
    }
    float4 o;
    o.x = (a0.x + a1.x) + (a2.x + a3.x);
    o.y = (a0.y + a1.y) + (a2.y + a3.y);
    o.z = (a0.z + a1.z) + (a2.z + a3.z);
    o.w = (a0.w + a1.w) + (a2.w + a3.w);
    *reinterpret_cast<float4*>(awe + (size_t)b * E_ + t * 4) = o;
}

extern "C" void kernel_launch(void* const* d_in, const int* in_sizes, int n_in,
                              void* d_out, int out_size, void* d_ws, size_t ws_size,
                              hipStream_t stream) {
    const float* enc  = (const float*)d_in[0];
    const float* dec  = (const float*)d_in[1];
    const int*   mask = (const int*)d_in[2];
    const float* We   = (const float*)d_in[3];
    const float* be   = (const float*)d_in[4];
    const float* Wd   = (const float*)d_in[5];
    const float* bd   = (const float*)d_in[6];
    const float* wf   = (const float*)d_in[7];
    const float* bf   = (const float*)d_in[8];

    float* awe   = (float*)d_out;                  // [256][2048]
    float* alpha = awe + (size_t)B_ * E_;          // [256][196]

    char* ws = (char*)d_ws;
    unsigned short* WeP = (unsigned short*)ws;                        // 2 MB
    float* bias2   = (float*)(ws + (2u << 20));                       // 512 KB
    float* scoresP = (float*)(ws + (2u << 20) + (512u << 10));        // 803 KB

    hipLaunchKernelGGL(k_wepack, dim3((E_ * A_) / 256), dim3(256), 0, stream, We, WeP);
    hipLaunchKernelGGL(k_bias2, dim3(B_), dim3(256), 0, stream, dec, Wd, be, bd, bias2);
    hipLaunchKernelGGL(k_gemm_score, dim3((M_TOT / 128) * 4), dim3(256), 0, stream,
                       enc, WeP, bias2, wf, scoresP);
    hipLaunchKernelGGL(k_softmax, dim3(B_), dim3(256), 0, stream, scoresP, mask, bf, alpha);
    hipLaunchKernelGGL(k_awe, dim3(B_), dim3(512), 0, stream, enc, alpha, awe);
}